// Round 4
// baseline (320.531 us; speedup 1.0000x reference)
//
#include <hip/hip_runtime.h>
#include <math.h>

// Problem constants (fixed by reference setup_inputs)
constexpr int B = 4, C = 16, H = 512, W = 512;
constexpr float EPSF = 1e-6f;
constexpr float INV_K = 1.0f / 9.0f;
constexpr float EXP_NEG_HALF = 0.60653065971263342f;  // exp(-0.5); THETA=1 => M = (feat+eps)*exp(-0.5)

// One thread computes 4 consecutive w-pixels (float4 granularity).
// Grid covers B*C*H*(W/4) threads.
__global__ __launch_bounds__(256) void texmart_kernel(const float* __restrict__ x,
                                                      float* __restrict__ out) {
    const int W4 = W / 4;
    int t  = blockIdx.x * blockDim.x + threadIdx.x;
    int w4 = t & (W4 - 1);          // 7 bits
    int h  = (t >> 7) & (H - 1);    // 9 bits
    int bc = t >> 16;               // b*C + c in [0, 64)
    int w0 = w4 << 2;

    const float* plane = x + (size_t)bc * (H * W);

    // row[r][j] = x[h-1+r][w0-1+j], zero padded at all borders
    float row[3][6];
#pragma unroll
    for (int r = 0; r < 3; ++r) {
        int hr = h - 1 + r;
        bool inb = (hr >= 0) && (hr < H);
        const float* rp = plane + (size_t)(inb ? hr : 0) * W;
        float4 v = make_float4(0.f, 0.f, 0.f, 0.f);
        if (inb) v = *reinterpret_cast<const float4*>(rp + w0);
        row[r][1] = v.x; row[r][2] = v.y; row[r][3] = v.z; row[r][4] = v.w;
        row[r][0] = (inb && w0 > 0)     ? rp[w0 - 1] : 0.f;
        row[r][5] = (inb && w0 + 4 < W) ? rp[w0 + 4] : 0.f;
    }

    float con[4], ene[4], ent[4], hom[4];
#pragma unroll
    for (int i = 0; i < 4; ++i) {
        // pass 1: sum, sum of squares, entropy accumulation
        float sum = 0.f, sumsq = 0.f, es = 0.f;
#pragma unroll
        for (int r = 0; r < 3; ++r) {
#pragma unroll
            for (int c = 0; c < 3; ++c) {
                float p = row[r][i + c];
                sum   += p;
                sumsq  = fmaf(p, p, sumsq);
                es     = fmaf(p, __logf(p + EPSF), es);
            }
        }
        float mean = sum * INV_K;
        // pass 2: explicit centered moments (avoid sumsq - 9*mean^2 cancellation)
        float ss = 0.f, sa = 0.f;
#pragma unroll
        for (int r = 0; r < 3; ++r) {
#pragma unroll
            for (int c = 0; c < 3; ++c) {
                float d = row[r][i + c] - mean;
                ss = fmaf(d, d, ss);
                sa += fabsf(d);
            }
        }
        float stdv = sqrtf(ss * 0.125f) + EPSF;  // ddof=1: ss/8
        con[i] = ss / (stdv * stdv) * INV_K;     // mean((centered/std)^2)
        ene[i] = sumsq * INV_K;
        ent[i] = -es * INV_K;
        hom[i] = 9.f / (9.f + sa);               // 1/(1 + mean|centered|)
    }

    // out[b, c*4 + f, h, w]; bc*4 + f is the output channel
    size_t obase = ((size_t)bc * 4) * (size_t)(H * W) + (size_t)h * W + w0;
    float* o = out + obase;
    const size_t PL = (size_t)H * W;

    float4 v0 = make_float4((con[0] + EPSF) * EXP_NEG_HALF, (con[1] + EPSF) * EXP_NEG_HALF,
                            (con[2] + EPSF) * EXP_NEG_HALF, (con[3] + EPSF) * EXP_NEG_HALF);
    float4 v1 = make_float4((ene[0] + EPSF) * EXP_NEG_HALF, (ene[1] + EPSF) * EXP_NEG_HALF,
                            (ene[2] + EPSF) * EXP_NEG_HALF, (ene[3] + EPSF) * EXP_NEG_HALF);
    float4 v2 = make_float4((ent[0] + EPSF) * EXP_NEG_HALF, (ent[1] + EPSF) * EXP_NEG_HALF,
                            (ent[2] + EPSF) * EXP_NEG_HALF, (ent[3] + EPSF) * EXP_NEG_HALF);
    float4 v3 = make_float4((hom[0] + EPSF) * EXP_NEG_HALF, (hom[1] + EPSF) * EXP_NEG_HALF,
                            (hom[2] + EPSF) * EXP_NEG_HALF, (hom[3] + EPSF) * EXP_NEG_HALF);

    *reinterpret_cast<float4*>(o)          = v0;
    *reinterpret_cast<float4*>(o + PL)     = v1;
    *reinterpret_cast<float4*>(o + 2 * PL) = v2;
    *reinterpret_cast<float4*>(o + 3 * PL) = v3;
}

extern "C" void kernel_launch(void* const* d_in, const int* in_sizes, int n_in,
                              void* d_out, int out_size, void* d_ws, size_t ws_size,
                              hipStream_t stream) {
    const float* x = (const float*)d_in[0];
    float* out = (float*)d_out;
    int total = B * C * H * (W / 4);          // 4,194,304 threads
    dim3 block(256);
    dim3 grid(total / 256);                   // 16384 blocks
    texmart_kernel<<<grid, block, 0, stream>>>(x, out);
}

// Round 7
// 312.847 us; speedup vs baseline: 1.0246x; 1.0246x over previous
//
#include <hip/hip_runtime.h>
#include <math.h>

// x: [4,16,512,512] f32 -> out: [4,64,512,512] f32
constexpr int H = 512, W = 512;
constexpr float EPSF = 1e-6f;
constexpr float INV_K = 1.0f / 9.0f;
constexpr float EXP_NEG_HALF = 0.60653065971263342f;  // THETA=1 => M = (feat+eps)*exp(-0.5)

// Load one padded row segment: row[0..5] = x[hr][w0-1 .. w0+4], zero-padded.
__device__ __forceinline__ void load_row(const float* __restrict__ plane, int hr, int w0,
                                         bool wl, bool wr, float row[6]) {
    if (hr >= 0 && hr < H) {
        const float* rp = plane + (size_t)hr * W;
        float4 v = *reinterpret_cast<const float4*>(rp + w0);
        row[1] = v.x; row[2] = v.y; row[3] = v.z; row[4] = v.w;
        row[0] = wl ? rp[w0 - 1] : 0.f;
        row[5] = wr ? rp[w0 + 4] : 0.f;
    } else {
#pragma unroll
        for (int j = 0; j < 6; ++j) row[j] = 0.f;
    }
}

__device__ __forceinline__ void pix_feats(const float r0[6], const float r1[6], const float r2[6],
                                          int i, float& con, float& ene, float& ent, float& hom) {
    float sum = 0.f, sumsq = 0.f, es = 0.f;
#pragma unroll
    for (int c = 0; c < 3; ++c) {
        float a = r0[i + c], b = r1[i + c], d = r2[i + c];
        sum += a + b + d;
        sumsq = fmaf(a, a, fmaf(b, b, fmaf(d, d, sumsq)));
        es = fmaf(a, __logf(a + EPSF), fmaf(b, __logf(b + EPSF), fmaf(d, __logf(d + EPSF), es)));
    }
    float mean = sum * INV_K;
    float ss = 0.f, sa = 0.f;
#pragma unroll
    for (int c = 0; c < 3; ++c) {
        float d0 = r0[i + c] - mean, d1 = r1[i + c] - mean, d2 = r2[i + c] - mean;
        ss = fmaf(d0, d0, fmaf(d1, d1, fmaf(d2, d2, ss)));
        sa += fabsf(d0) + fabsf(d1) + fabsf(d2);
    }
    float stdv = sqrtf(ss * 0.125f) + EPSF;   // ddof=1: ss/8
    con = ss / (stdv * stdv) * INV_K;
    ene = sumsq * INV_K;
    ent = -es * INV_K;
    hom = 9.f / (9.f + sa);
}

// One thread computes a 4(h) x 4(w) pixel tile with a rolling 3-row register
// window: rows load once per thread (1.5x global redundancy vs 3x for the
// row-per-thread version), next row issued before current row's compute.
__global__ __launch_bounds__(256) void texmart_kernel(const float* __restrict__ x,
                                                      float* __restrict__ out) {
    int t  = blockIdx.x * 256 + threadIdx.x;
    int w4 = t & 127;           // W/4 = 128
    int hg = (t >> 7) & 127;    // H/4 = 128
    int bc = t >> 14;           // b*C + c in [0,64)
    int w0 = w4 << 2;
    int h0 = hg << 2;
    bool wl = (w0 > 0), wr = (w0 + 4 < W);

    const float* plane = x + (size_t)bc * (H * W);
    const size_t PL = (size_t)H * W;
    float* obase = out + (size_t)(bc * 4) * PL + w0;

    float r0[6], r1[6], r2[6], nxt[6];
    load_row(plane, h0 - 1, w0, wl, wr, r0);
    load_row(plane, h0,     w0, wl, wr, r1);
    load_row(plane, h0 + 1, w0, wl, wr, r2);

#pragma unroll
    for (int rr = 0; rr < 4; ++rr) {
        // issue next row's loads first so they hide under this row's compute
        if (rr < 3) load_row(plane, h0 + rr + 2, w0, wl, wr, nxt);

        float con[4], ene[4], ent[4], hom[4];
#pragma unroll
        for (int i = 0; i < 4; ++i)
            pix_feats(r0, r1, r2, i, con[i], ene[i], ent[i], hom[i]);

        float* o = obase + (size_t)(h0 + rr) * W;
        *reinterpret_cast<float4*>(o) =
            make_float4((con[0] + EPSF) * EXP_NEG_HALF, (con[1] + EPSF) * EXP_NEG_HALF,
                        (con[2] + EPSF) * EXP_NEG_HALF, (con[3] + EPSF) * EXP_NEG_HALF);
        *reinterpret_cast<float4*>(o + PL) =
            make_float4((ene[0] + EPSF) * EXP_NEG_HALF, (ene[1] + EPSF) * EXP_NEG_HALF,
                        (ene[2] + EPSF) * EXP_NEG_HALF, (ene[3] + EPSF) * EXP_NEG_HALF);
        *reinterpret_cast<float4*>(o + 2 * PL) =
            make_float4((ent[0] + EPSF) * EXP_NEG_HALF, (ent[1] + EPSF) * EXP_NEG_HALF,
                        (ent[2] + EPSF) * EXP_NEG_HALF, (ent[3] + EPSF) * EXP_NEG_HALF);
        *reinterpret_cast<float4*>(o + 3 * PL) =
            make_float4((hom[0] + EPSF) * EXP_NEG_HALF, (hom[1] + EPSF) * EXP_NEG_HALF,
                        (hom[2] + EPSF) * EXP_NEG_HALF, (hom[3] + EPSF) * EXP_NEG_HALF);

        if (rr < 3) {
#pragma unroll
            for (int j = 0; j < 6; ++j) { r0[j] = r1[j]; r1[j] = r2[j]; r2[j] = nxt[j]; }
        }
    }
}

extern "C" void kernel_launch(void* const* d_in, const int* in_sizes, int n_in,
                              void* d_out, int out_size, void* d_ws, size_t ws_size,
                              hipStream_t stream) {
    const float* x = (const float*)d_in[0];
    float* out = (float*)d_out;
    // threads = 64 planes * 128 hg * 128 w4 = 1,048,576
    dim3 block(256);
    dim3 grid(4096);
    texmart_kernel<<<grid, block, 0, stream>>>(x, out);
}